// Round 17
// baseline (199.445 us; speedup 1.0000x reference)
//
#include <hip/hip_runtime.h>
#include <hip/hip_bf16.h>

#define NH 12
#define HD 64
#define SEQ 2048
#define DM 768

typedef __attribute__((ext_vector_type(8))) short bf16x8;
typedef __attribute__((ext_vector_type(4))) short bf16x4;
typedef __attribute__((ext_vector_type(4))) float f32x4;

static __device__ __forceinline__ unsigned short f2bf(float f) {
  unsigned int u = __float_as_uint(f);
  u += 0x7fff + ((u >> 16) & 1);   // round-to-nearest-even
  return (unsigned short)(u >> 16);
}

static __device__ __forceinline__ unsigned cvt_pk_bf16(float lo, float hi) {
  unsigned r;
  asm("v_cvt_pk_bf16_f32 %0, %1, %2" : "=v"(r) : "v"(lo), "v"(hi));
  return r;
}

static __device__ __forceinline__ void gload_lds16(const void* g, void* l) {
  __builtin_amdgcn_global_load_lds(
      (const __attribute__((address_space(1))) void*)g,
      (__attribute__((address_space(3))) void*)l, 16, 0, 0);
}

// q-store scale: sqrt(log2(e))/8 — folds the 1/64 attention scale and the
// base-2 exp conversion into q at the QKV store.
#define QSCALE 0.15014030f

// ---------------------------------------------------------------------------
// Kernel 0: f32 -> bf16 bulk convert, 3 segments in one launch.
// ---------------------------------------------------------------------------
__global__ __launch_bounds__(256) void cvt3_kernel(
    const float* __restrict__ s0, unsigned short* __restrict__ d0, int n0,
    const float* __restrict__ s1, unsigned short* __restrict__ d1, int n1,
    const float* __restrict__ s2, unsigned short* __restrict__ d2, int n2) {
  int i = blockIdx.x * 256 + threadIdx.x;
  const int stride = gridDim.x * 256;
  const int ntot = n0 + n1 + n2;
  for (; i < ntot; i += stride) {
    const float* src;
    unsigned short* dst;
    int j = i;
    if (j < n0) { src = s0; dst = d0; }
    else if (j < n0 + n1) { j -= n0; src = s1; dst = d1; }
    else { j -= n0 + n1; src = s2; dst = d2; }
    const float4 a = reinterpret_cast<const float4*>(src)[j * 2];
    const float4 b = reinterpret_cast<const float4*>(src)[j * 2 + 1];
    ushort4 lo = make_ushort4(f2bf(a.x), f2bf(a.y), f2bf(a.z), f2bf(a.w));
    ushort4 hi = make_ushort4(f2bf(b.x), f2bf(b.y), f2bf(b.z), f2bf(b.w));
    reinterpret_cast<ushort4*>(dst)[j * 2] = lo;
    reinterpret_cast<ushort4*>(dst)[j * 2 + 1] = hi;
  }
}

// ---------------------------------------------------------------------------
// Kernel 1: qkv = xb @ wb^T + b (bf16 in). R14 config (best measured):
// 128x128 tile, BK=64, dbuf LDS via global_load_lds, XOR row-swizzle,
// XCD-affinity grid. q stored (B,H,S,HD) pre-scaled by QSCALE; v stored
// (B,H,HD,S) k-permuted (attn PV layout).
// ---------------------------------------------------------------------------
__global__ __launch_bounds__(256) void qkv_kernel(
    const unsigned short* __restrict__ xb, const unsigned short* __restrict__ wb,
    const float* __restrict__ bias,
    unsigned short* __restrict__ qb, unsigned short* __restrict__ vtb) {
  __shared__ alignas(16) char As[2][16384];   // [128 rows][128B], XOR-swizzled
  __shared__ alignas(16) char Bs[2][16384];
  const int tid = threadIdx.x;
  const int lane = tid & 63, wid = tid >> 6;
  const int wr = wid >> 1, wc = wid & 1;
  const int g = lane >> 4, c = lane & 15;

  // XCD-affinity decode: wg = xcd + 8*(m_local + 8*n_idx)
  const int wg = blockIdx.x;
  const int xcd = wg & 7;
  const int idx = wg >> 3;                 // 0..95
  const int m0 = (xcd * 8 + (idx & 7)) * 128;
  const int n0 = (idx >> 3) * 128;         // 0..11 blocks
  const char* Ab = (const char*)xb;
  const char* Bb = (const char*)wb;

  auto stage = [&](int kt, int buf) {
    const int k0b = kt * 128;
#pragma unroll
    for (int i = 0; i < 4; ++i) {
      const int o = tid * 16 + i * 4096;
      const int row = o >> 7;
      const int colb = (o & 127) ^ ((row & 7) << 4);
      gload_lds16(Ab + (size_t)(m0 + row) * 1536 + k0b + colb, &As[buf][o]);
      gload_lds16(Bb + (size_t)(n0 + row) * 1536 + k0b + colb, &Bs[buf][o]);
    }
  };

  f32x4 acc[4][4] = {};
  stage(0, 0);

  for (int kt = 0; kt < 12; ++kt) {
    __syncthreads();                       // drains vmcnt: stage(kt) landed
    if (kt < 11) stage(kt + 1, (kt + 1) & 1);
    const char* Ap = As[kt & 1];
    const char* Bp = Bs[kt & 1];
    bf16x8 a_f[4][2], b_f[4][2];
#pragma unroll
    for (int i = 0; i < 4; ++i) {
      const int ra = wr * 64 + i * 16 + c;
      const int rb = wc * 64 + i * 16 + c;
      const int sa = (ra & 7) << 4, sb = (rb & 7) << 4;
#pragma unroll
      for (int ks = 0; ks < 2; ++ks) {
        a_f[i][ks] = *reinterpret_cast<const bf16x8*>(Ap + ra * 128 + ((ks * 64 + g * 16) ^ sa));
        b_f[i][ks] = *reinterpret_cast<const bf16x8*>(Bp + rb * 128 + ((ks * 64 + g * 16) ^ sb));
      }
    }
#pragma unroll
    for (int ai = 0; ai < 4; ++ai)
#pragma unroll
      for (int ni = 0; ni < 4; ++ni) {
        acc[ai][ni] = __builtin_amdgcn_mfma_f32_16x16x32_bf16(a_f[ai][0], b_f[ni][0], acc[ai][ni], 0, 0, 0);
        acc[ai][ni] = __builtin_amdgcn_mfma_f32_16x16x32_bf16(a_f[ai][1], b_f[ni][1], acc[ai][ni], 0, 0, 0);
      }
  }

#pragma unroll
  for (int ni = 0; ni < 4; ++ni) {
    const int n = n0 + wc * 64 + ni * 16 + c;
    const float bn = bias[n];
    if (n < DM) {  // q path: (B,H,S,HD), pre-scaled
      const int h = n >> 6, d = n & 63;
#pragma unroll
      for (int ai = 0; ai < 4; ++ai)
#pragma unroll
        for (int r = 0; r < 4; ++r) {
          const int m = m0 + wr * 64 + ai * 16 + g * 4 + r;
          const int bb = m >> 11, s = m & 2047;
          qb[(((size_t)(bb * NH + h)) * SEQ + s) * HD + d] = f2bf((acc[ai][ni][r] + bn) * QSCALE);
        }
    } else {  // v path: transposed (B,H,HD,S), k-permuted within 32-blocks:
      // off_perm = (off&3) | ((off>>4)&1)<<2 | ((off>>2)&3)<<3
      const int nn = n - DM;
      const int h = nn >> 6, d = nn & 63;
#pragma unroll
      for (int ai = 0; ai < 4; ++ai) {
        const int m_base = m0 + wr * 64 + ai * 16 + g * 4;
        const int bb = m_base >> 11, s0 = m_base & 2047;
        const int blk = s0 >> 5, off = s0 & 31;
        const int offp = (((off >> 4) & 1) << 2) + (((off >> 2) & 3) << 3);
        ushort4 pk = make_ushort4(f2bf(acc[ai][ni][0] + bn), f2bf(acc[ai][ni][1] + bn),
                                  f2bf(acc[ai][ni][2] + bn), f2bf(acc[ai][ni][3] + bn));
        *reinterpret_cast<ushort4*>(
            &vtb[((size_t)(bb * NH + h) * HD + d) * SEQ + blk * 32 + offp]) = pk;
      }
    }
  }
}

// ---------------------------------------------------------------------------
// Kernel 2: flash attention, Q == K (pre-scaled), fixed-max base-2 softmax,
// 2x2 wave split, PV at full K=32 via permuted-V layout, grid 1536.
// NEW: cross-tile pipeline — QK(t+1) issued BEFORE softmax(t)/PV(t) so exp2
// VALU interleaves with next tile's MFMA stream. K 2-buf + V 3-buf = 40960 B
// LDS keeps the 4-blocks/CU cap. stage(t+2) issued mid-iter after lgkmcnt(0)
// (rule-18 fence); vmcnt(0)+barrier at iter top = same hazard invariant as
// the verified R14 schedule.
// ---------------------------------------------------------------------------
__global__ __launch_bounds__(256, 4) void attn_kernel(
    const unsigned short* __restrict__ qb, const unsigned short* __restrict__ vtb,
    unsigned short* __restrict__ ao) {
  __shared__ alignas(16) char pool[40960];   // Kbuf[2][8192] | Vbuf[3][8192]
  char* Kbuf = pool;
  char* Vbuf = pool + 16384;

  const int tid = threadIdx.x;
  const int lane = tid & 63, wid = tid >> 6;
  const int g = lane >> 4, c = lane & 15;
  const int wq = wid >> 1, wk = wid & 1;

  // XCD-grouped decode: all 32 q-blocks of a bh on one XCD
  const int wg = blockIdx.x;
  const int xcd = wg & 7;
  const int idx = wg >> 3;                 // 0..191
  const int bh = xcd * 6 + (idx >> 5);
  const int qs0 = (idx & 31) * 64;
  const size_t base = (size_t)bh * SEQ * HD;

  // Q B-frags: lane (c,g) holds Q[qs0+wq*32+jq*16+c][ks*32+g*8..+7]
  bf16x8 qf[2][2];
#pragma unroll
  for (int jq = 0; jq < 2; ++jq) {
    const unsigned short* qrow = &qb[base + (size_t)(qs0 + wq * 32 + jq * 16 + c) * HD + g * 8];
    qf[jq][0] = *reinterpret_cast<const bf16x8*>(qrow);
    qf[jq][1] = *reinterpret_cast<const bf16x8*>(qrow + 32);
  }

  const char* qbB = (const char*)qb;
  const char* vtB = (const char*)vtb;
  const int oK0 = tid * 16, oK1 = tid * 16 + 4096;
  const int swK0 = oK0 ^ (((oK0 >> 7) & 7) << 4);
  const int swK1 = oK1 ^ (((oK1 >> 7) & 7) << 4);
  const int rV0 = oK0 >> 7, rV1 = oK1 >> 7;
  const int swV0 = (oK0 & 127) ^ ((rV0 & 7) << 4);
  const int swV1 = (oK1 & 127) ^ ((rV1 & 7) << 4);

  auto stage = [&](int t) {
    char* Kd = Kbuf + (t & 1) * 8192;
    char* Vd = Vbuf + (t % 3) * 8192;
    const size_t kQ = base * 2 + (size_t)t * 8192;   // K tile: contiguous 8KB
    gload_lds16(qbB + kQ + swK0, Kd + oK0);
    gload_lds16(qbB + kQ + swK1, Kd + oK1);
    gload_lds16(vtB + ((size_t)(bh * HD + rV0) * SEQ + t * 64) * 2 + swV0, Vd + oK0);
    gload_lds16(vtB + ((size_t)(bh * HD + rV1) * SEQ + t * 64) * 2 + swV1, Vd + oK1);
  };

  float l_p[2] = {0.f, 0.f};
  f32x4 o_acc[4][2] = {};  // [dn][jq]: O[d=dn*16+4g+r][q=qs0+wq*32+jq*16+c], partial wk
  const int cswz = (c & 7) << 4;

  // QK of tile t1 (K from Kbuf[t1&1]) -> scores s
  auto qk = [&](int t1, f32x4 (&s)[2][2]) {
    const char* Kp = Kbuf + (t1 & 1) * 8192;
#pragma unroll
    for (int jp = 0; jp < 2; ++jp)
#pragma unroll
      for (int jq = 0; jq < 2; ++jq) s[jp][jq] = f32x4{0.f, 0.f, 0.f, 0.f};
    __builtin_amdgcn_s_setprio(1);
#pragma unroll
    for (int jp = 0; jp < 2; ++jp) {
      const int krow = wk * 32 + jp * 16 + c;
      const bf16x8 kf0 = *reinterpret_cast<const bf16x8*>(Kp + krow * 128 + ((g * 16) ^ cswz));
      const bf16x8 kf1 = *reinterpret_cast<const bf16x8*>(Kp + krow * 128 + ((64 + g * 16) ^ cswz));
#pragma unroll
      for (int jq = 0; jq < 2; ++jq) {
        s[jp][jq] = __builtin_amdgcn_mfma_f32_16x16x32_bf16(kf0, qf[jq][0], s[jp][jq], 0, 0, 0);
        s[jp][jq] = __builtin_amdgcn_mfma_f32_16x16x32_bf16(kf1, qf[jq][1], s[jp][jq], 0, 0, 0);
      }
    }
    __builtin_amdgcn_s_setprio(0);
  };

  // softmax(t) from cur + PV(t); issues stage(t+2) after the V reads retire
  auto smpv = [&](int t, f32x4 (&cur)[2][2]) {
    // fixed-max base-2 softmax; pvv[jq] slot e: k = wk*32+(e>=4?16:0)+4g+(e&3)
    bf16x8 pvv[2];
#pragma unroll
    for (int jq = 0; jq < 2; ++jq) {
      float a0 = __builtin_amdgcn_exp2f(cur[0][jq][0]);
      float a1 = __builtin_amdgcn_exp2f(cur[0][jq][1]);
      float a2 = __builtin_amdgcn_exp2f(cur[0][jq][2]);
      float a3 = __builtin_amdgcn_exp2f(cur[0][jq][3]);
      float b0 = __builtin_amdgcn_exp2f(cur[1][jq][0]);
      float b1 = __builtin_amdgcn_exp2f(cur[1][jq][1]);
      float b2 = __builtin_amdgcn_exp2f(cur[1][jq][2]);
      float b3 = __builtin_amdgcn_exp2f(cur[1][jq][3]);
      l_p[jq] += ((a0 + a1) + (a2 + a3)) + ((b0 + b1) + (b2 + b3));
      uint4 u = make_uint4(cvt_pk_bf16(a0, a1), cvt_pk_bf16(a2, a3),
                           cvt_pk_bf16(b0, b1), cvt_pk_bf16(b2, b3));
      pvv[jq] = *reinterpret_cast<bf16x8*>(&u);
    }
    // V A-frags (one b128 each, permuted layout)
    const char* Vp = Vbuf + (t % 3) * 8192;
    bf16x8 av[4];
#pragma unroll
    for (int dn = 0; dn < 4; ++dn) {
      const int vrow = dn * 16 + c;
      av[dn] = *reinterpret_cast<const bf16x8*>(
          Vp + vrow * 128 + ((wk * 64 + 16 * g) ^ ((vrow & 7) << 4)));
    }
    asm volatile("s_waitcnt lgkmcnt(0)" ::: "memory");  // all LDS reads retired
    __builtin_amdgcn_sched_barrier(0);
    if (t <= 29) stage(t + 2);           // into Kbuf[t&1] / Vbuf[(t+2)%3] (safe)
    __builtin_amdgcn_s_setprio(1);
#pragma unroll
    for (int dn = 0; dn < 4; ++dn)
#pragma unroll
      for (int jq = 0; jq < 2; ++jq)
        o_acc[dn][jq] = __builtin_amdgcn_mfma_f32_16x16x32_bf16(av[dn], pvv[jq], o_acc[dn][jq], 0, 0, 0);
    __builtin_amdgcn_s_setprio(0);
  };

  auto iter = [&](int t, f32x4 (&cur)[2][2], f32x4 (&nxt)[2][2]) {
    asm volatile("s_waitcnt vmcnt(0)" ::: "memory");   // stage(t+1) landed
    __builtin_amdgcn_sched_barrier(0);
    __builtin_amdgcn_s_barrier();                      // all waves: bufs ready
    if (t < 31) qk(t + 1, nxt);                        // MFMA stream ...
    smpv(t, cur);                                      // ... overlaps exp2 VALU
  };

  // prologue
  stage(0);
  stage(1);
  asm volatile("s_waitcnt vmcnt(4)" ::: "memory");     // tile 0 landed
  __builtin_amdgcn_sched_barrier(0);
  __builtin_amdgcn_s_barrier();
  f32x4 saA[2][2], saB[2][2];
  qk(0, saA);

  for (int tp = 0; tp < 32; tp += 2) {
    iter(tp, saA, saB);
    iter(tp + 1, saB, saA);
  }

  // ---- epilogue: reduce l over g; O + l over the wk pair via LDS ----
#pragma unroll
  for (int jq = 0; jq < 2; ++jq) {
    float v = l_p[jq];
    v += __shfl_xor(v, 16);
    v += __shfl_xor(v, 32);
    l_p[jq] = v;
  }
  __syncthreads();   // all reads of pool done; reuse as exchange scratch

  float* ex = (float*)(pool + wq * 16384);  // [32 q][68] f32 + l[32]
  float* exl = ex + 32 * 68;
  if (wk == 1) {
#pragma unroll
    for (int dn = 0; dn < 4; ++dn)
#pragma unroll
      for (int jq = 0; jq < 2; ++jq)
        *reinterpret_cast<f32x4*>(&ex[(jq * 16 + c) * 68 + dn * 16 + 4 * g]) = o_acc[dn][jq];
    if (g == 0) {
      exl[c] = l_p[0];
      exl[16 + c] = l_p[1];
    }
  }
  __syncthreads();
  if (wk == 0) {
    const int b = bh / NH, h = bh % NH;
    float linv[2];
#pragma unroll
    for (int jq = 0; jq < 2; ++jq)
      linv[jq] = __builtin_amdgcn_rcpf(l_p[jq] + exl[jq * 16 + c]);
#pragma unroll
    for (int dn = 0; dn < 4; ++dn)
#pragma unroll
      for (int jq = 0; jq < 2; ++jq) {
        f32x4 o = o_acc[dn][jq];
        o += *reinterpret_cast<const f32x4*>(&ex[(jq * 16 + c) * 68 + dn * 16 + 4 * g]);
        uint2 wv = make_uint2(cvt_pk_bf16(o[0] * linv[jq], o[1] * linv[jq]),
                              cvt_pk_bf16(o[2] * linv[jq], o[3] * linv[jq]));
        *reinterpret_cast<uint2*>(
            &ao[((size_t)b * SEQ + qs0 + wq * 32 + jq * 16 + c) * DM + h * HD + dn * 16 + 4 * g]) = wv;
      }
  }
}

// ---------------------------------------------------------------------------
// Kernel 3: out = ao @ pwb^T + proj_b (bf16 in, f32 out). 64x128 tile, BK=64,
// XCD-affinity 1D grid (each XCD owns a 16-block m-panel).
// ---------------------------------------------------------------------------
__global__ __launch_bounds__(256) void proj_kernel(
    const unsigned short* __restrict__ ao, const unsigned short* __restrict__ pwb,
    const float* __restrict__ bias, float* __restrict__ out) {
  __shared__ alignas(16) char As[2][8192];    // [64 m rows][128B]
  __shared__ alignas(16) char Bs[2][16384];   // [128 n rows][128B]
  const int tid = threadIdx.x;
  const int lane = tid & 63, wid = tid >> 6;
  const int g = lane >> 4, c = lane & 15;

  // XCD-affinity decode: wg = xcd + 8*(m_local + 16*n_idx)
  const int wg = blockIdx.x;
  const int xcd = wg & 7;
  const int idx = wg >> 3;                 // 0..95
  const int m0 = (xcd * 16 + (idx & 15)) * 64;
  const int n0 = (idx >> 4) * 128;         // 0..5
  const char* Ab = (const char*)ao;
  const char* Bb = (const char*)pwb;

  auto stage = [&](int kt, int buf) {
    const int k0b = kt * 128;
#pragma unroll
    for (int i = 0; i < 2; ++i) {
      const int o = tid * 16 + i * 4096;
      const int row = o >> 7;
      const int colb = (o & 127) ^ ((row & 7) << 4);
      gload_lds16(Ab + (size_t)(m0 + row) * 1536 + k0b + colb, &As[buf][o]);
    }
#pragma unroll
    for (int i = 0; i < 4; ++i) {
      const int o = tid * 16 + i * 4096;
      const int row = o >> 7;
      const int colb = (o & 127) ^ ((row & 7) << 4);
      gload_lds16(Bb + (size_t)(n0 + row) * 1536 + k0b + colb, &Bs[buf][o]);
    }
  };

  f32x4 acc[4][2] = {};   // [mi][nj]: m = mi*16, n = wid*32 + nj*16
  stage(0, 0);

  for (int kt = 0; kt < 12; ++kt) {
    __syncthreads();
    if (kt < 11) stage(kt + 1, (kt + 1) & 1);
    const char* Ap = As[kt & 1];
    const char* Bp = Bs[kt & 1];
    bf16x8 a_f[4][2], b_f[2][2];
#pragma unroll
    for (int i = 0; i < 4; ++i) {
      const int ra = i * 16 + c;
      const int sa = (ra & 7) << 4;
#pragma unroll
      for (int ks = 0; ks < 2; ++ks)
        a_f[i][ks] = *reinterpret_cast<const bf16x8*>(Ap + ra * 128 + ((ks * 64 + g * 16) ^ sa));
    }
#pragma unroll
    for (int j = 0; j < 2; ++j) {
      const int rb = wid * 32 + j * 16 + c;
      const int sb = (rb & 7) << 4;
#pragma unroll
      for (int ks = 0; ks < 2; ++ks)
        b_f[j][ks] = *reinterpret_cast<const bf16x8*>(Bp + rb * 128 + ((ks * 64 + g * 16) ^ sb));
    }
#pragma unroll
    for (int i = 0; i < 4; ++i)
#pragma unroll
      for (int j = 0; j < 2; ++j) {
        acc[i][j] = __builtin_amdgcn_mfma_f32_16x16x32_bf16(a_f[i][0], b_f[j][0], acc[i][j], 0, 0, 0);
        acc[i][j] = __builtin_amdgcn_mfma_f32_16x16x32_bf16(a_f[i][1], b_f[j][1], acc[i][j], 0, 0, 0);
      }
  }

#pragma unroll
  for (int j = 0; j < 2; ++j) {
    const int n = n0 + wid * 32 + j * 16 + c;
    const float bn = bias[n];
#pragma unroll
    for (int i = 0; i < 4; ++i)
#pragma unroll
      for (int r = 0; r < 4; ++r) {
        const int m = m0 + i * 16 + g * 4 + r;
        out[(size_t)m * DM + n] = acc[i][j][r] + bn;
      }
  }
}

extern "C" void kernel_launch(void* const* d_in, const int* in_sizes, int n_in,
                              void* d_out, int out_size, void* d_ws, size_t ws_size,
                              hipStream_t stream) {
  const float* x = (const float*)d_in[0];
  const float* qkv_w = (const float*)d_in[1];
  const float* qkv_b = (const float*)d_in[2];
  const float* proj_w = (const float*)d_in[3];
  const float* proj_b = (const float*)d_in[4];
  float* out = (float*)d_out;

  const size_t elems = (size_t)4 * NH * SEQ * HD;  // 6291456 = B*S*DM
  unsigned short* qbuf = (unsigned short*)d_ws;
  unsigned short* vtbuf = qbuf + elems;
  unsigned short* xbf = vtbuf + elems;       // aliases aobuf (disjoint lifetimes)
  unsigned short* aobuf = xbf;
  unsigned short* wqkvbf = xbf + elems;      // 1179648
  unsigned short* wprojbf = wqkvbf + (size_t)2 * DM * DM;  // 589824

  cvt3_kernel<<<dim3(2048), 256, 0, stream>>>(
      x, xbf, (int)(elems / 8),
      qkv_w, wqkvbf, 2 * DM * DM / 8,
      proj_w, wprojbf, DM * DM / 8);

  qkv_kernel<<<dim3(768), 256, 0, stream>>>(xbf, wqkvbf, qkv_b, qbuf, vtbuf);
  attn_kernel<<<dim3(1536), 256, 0, stream>>>(qbuf, vtbuf, aobuf);
  proj_kernel<<<dim3(768), 256, 0, stream>>>(aobuf, wprojbf, proj_b, out);
}

// Round 18
// 116.318 us; speedup vs baseline: 1.7147x; 1.7147x over previous
//
#include <hip/hip_runtime.h>
#include <hip/hip_bf16.h>

#define NH 12
#define HD 64
#define SEQ 2048
#define DM 768

typedef __attribute__((ext_vector_type(8))) short bf16x8;
typedef __attribute__((ext_vector_type(4))) short bf16x4;
typedef __attribute__((ext_vector_type(4))) float f32x4;

static __device__ __forceinline__ unsigned short f2bf(float f) {
  unsigned int u = __float_as_uint(f);
  u += 0x7fff + ((u >> 16) & 1);   // round-to-nearest-even
  return (unsigned short)(u >> 16);
}

static __device__ __forceinline__ unsigned cvt_pk_bf16(float lo, float hi) {
  unsigned r;
  asm("v_cvt_pk_bf16_f32 %0, %1, %2" : "=v"(r) : "v"(lo), "v"(hi));
  return r;
}

static __device__ __forceinline__ void gload_lds16(const void* g, void* l) {
  __builtin_amdgcn_global_load_lds(
      (const __attribute__((address_space(1))) void*)g,
      (__attribute__((address_space(3))) void*)l, 16, 0, 0);
}

// q-store scale: sqrt(log2(e))/8 — folds the 1/64 attention scale and the
// base-2 exp conversion into q at the QKV store.
#define QSCALE 0.15014030f

// ---------------------------------------------------------------------------
// Kernel 0: f32 -> bf16 bulk convert, 3 segments in one launch.
// ---------------------------------------------------------------------------
__global__ __launch_bounds__(256) void cvt3_kernel(
    const float* __restrict__ s0, unsigned short* __restrict__ d0, int n0,
    const float* __restrict__ s1, unsigned short* __restrict__ d1, int n1,
    const float* __restrict__ s2, unsigned short* __restrict__ d2, int n2) {
  int i = blockIdx.x * 256 + threadIdx.x;
  const int stride = gridDim.x * 256;
  const int ntot = n0 + n1 + n2;
  for (; i < ntot; i += stride) {
    const float* src;
    unsigned short* dst;
    int j = i;
    if (j < n0) { src = s0; dst = d0; }
    else if (j < n0 + n1) { j -= n0; src = s1; dst = d1; }
    else { j -= n0 + n1; src = s2; dst = d2; }
    const float4 a = reinterpret_cast<const float4*>(src)[j * 2];
    const float4 b = reinterpret_cast<const float4*>(src)[j * 2 + 1];
    ushort4 lo = make_ushort4(f2bf(a.x), f2bf(a.y), f2bf(a.z), f2bf(a.w));
    ushort4 hi = make_ushort4(f2bf(b.x), f2bf(b.y), f2bf(b.z), f2bf(b.w));
    reinterpret_cast<ushort4*>(dst)[j * 2] = lo;
    reinterpret_cast<ushort4*>(dst)[j * 2 + 1] = hi;
  }
}

// ---------------------------------------------------------------------------
// Kernel 1: qkv = xb @ wb^T + b (bf16 in). m97-proven shape: 128x128 tile,
// BK=64, dbuf LDS (64KB) via global_load_lds, XOR row-swizzle. XCD-affinity
// 1D grid: each XCD owns an 8-block m-panel (A L2-resident). q stored
// (B,H,S,HD) pre-scaled by QSCALE; v stored (B,H,HD,S) k-permuted (attn PV).
// ---------------------------------------------------------------------------
__global__ __launch_bounds__(256) void qkv_kernel(
    const unsigned short* __restrict__ xb, const unsigned short* __restrict__ wb,
    const float* __restrict__ bias,
    unsigned short* __restrict__ qb, unsigned short* __restrict__ vtb) {
  __shared__ alignas(16) char As[2][16384];   // [128 rows][128B], XOR-swizzled
  __shared__ alignas(16) char Bs[2][16384];
  const int tid = threadIdx.x;
  const int lane = tid & 63, wid = tid >> 6;
  const int wr = wid >> 1, wc = wid & 1;
  const int g = lane >> 4, c = lane & 15;

  // XCD-affinity decode: wg = xcd + 8*(m_local + 8*n_idx)
  const int wg = blockIdx.x;
  const int xcd = wg & 7;
  const int idx = wg >> 3;                 // 0..95
  const int m0 = (xcd * 8 + (idx & 7)) * 128;
  const int n0 = (idx >> 3) * 128;         // 0..11 blocks
  const char* Ab = (const char*)xb;
  const char* Bb = (const char*)wb;

  auto stage = [&](int kt, int buf) {
    const int k0b = kt * 128;
#pragma unroll
    for (int i = 0; i < 4; ++i) {
      const int o = tid * 16 + i * 4096;
      const int row = o >> 7;
      const int colb = (o & 127) ^ ((row & 7) << 4);
      gload_lds16(Ab + (size_t)(m0 + row) * 1536 + k0b + colb, &As[buf][o]);
      gload_lds16(Bb + (size_t)(n0 + row) * 1536 + k0b + colb, &Bs[buf][o]);
    }
  };

  f32x4 acc[4][4] = {};
  stage(0, 0);

  for (int kt = 0; kt < 12; ++kt) {
    __syncthreads();                       // drains vmcnt: stage(kt) landed
    if (kt < 11) stage(kt + 1, (kt + 1) & 1);
    const char* Ap = As[kt & 1];
    const char* Bp = Bs[kt & 1];
    bf16x8 a_f[4][2], b_f[4][2];
#pragma unroll
    for (int i = 0; i < 4; ++i) {
      const int ra = wr * 64 + i * 16 + c;
      const int rb = wc * 64 + i * 16 + c;
      const int sa = (ra & 7) << 4, sb = (rb & 7) << 4;
#pragma unroll
      for (int ks = 0; ks < 2; ++ks) {
        a_f[i][ks] = *reinterpret_cast<const bf16x8*>(Ap + ra * 128 + ((ks * 64 + g * 16) ^ sa));
        b_f[i][ks] = *reinterpret_cast<const bf16x8*>(Bp + rb * 128 + ((ks * 64 + g * 16) ^ sb));
      }
    }
#pragma unroll
    for (int ai = 0; ai < 4; ++ai)
#pragma unroll
      for (int ni = 0; ni < 4; ++ni) {
        acc[ai][ni] = __builtin_amdgcn_mfma_f32_16x16x32_bf16(a_f[ai][0], b_f[ni][0], acc[ai][ni], 0, 0, 0);
        acc[ai][ni] = __builtin_amdgcn_mfma_f32_16x16x32_bf16(a_f[ai][1], b_f[ni][1], acc[ai][ni], 0, 0, 0);
      }
  }

#pragma unroll
  for (int ni = 0; ni < 4; ++ni) {
    const int n = n0 + wc * 64 + ni * 16 + c;
    const float bn = bias[n];
    if (n < DM) {  // q path: (B,H,S,HD), pre-scaled
      const int h = n >> 6, d = n & 63;
#pragma unroll
      for (int ai = 0; ai < 4; ++ai)
#pragma unroll
        for (int r = 0; r < 4; ++r) {
          const int m = m0 + wr * 64 + ai * 16 + g * 4 + r;
          const int bb = m >> 11, s = m & 2047;
          qb[(((size_t)(bb * NH + h)) * SEQ + s) * HD + d] = f2bf((acc[ai][ni][r] + bn) * QSCALE);
        }
    } else {  // v path: transposed (B,H,HD,S), k-permuted within 32-blocks:
      // off_perm = (off&3) | ((off>>4)&1)<<2 | ((off>>2)&3)<<3
      const int nn = n - DM;
      const int h = nn >> 6, d = nn & 63;
#pragma unroll
      for (int ai = 0; ai < 4; ++ai) {
        const int m_base = m0 + wr * 64 + ai * 16 + g * 4;
        const int bb = m_base >> 11, s0 = m_base & 2047;
        const int blk = s0 >> 5, off = s0 & 31;
        const int offp = (((off >> 4) & 1) << 2) + (((off >> 2) & 3) << 3);
        ushort4 pk = make_ushort4(f2bf(acc[ai][ni][0] + bn), f2bf(acc[ai][ni][1] + bn),
                                  f2bf(acc[ai][ni][2] + bn), f2bf(acc[ai][ni][3] + bn));
        *reinterpret_cast<ushort4*>(
            &vtb[((size_t)(bb * NH + h) * HD + d) * SEQ + blk * 32 + offp]) = pk;
      }
    }
  }
}

// ---------------------------------------------------------------------------
// Kernel 2: flash attention (best measured 63.0us): Q == K pre-scaled,
// fixed-max base-2 softmax, 2x2 wave split, PV at full K=32 via permuted-V
// layout, double-buffered gload_lds, grid 1536 (4-blocks/CU cap + back-fill).
// ---------------------------------------------------------------------------
__global__ __launch_bounds__(256, 4) void attn_kernel(
    const unsigned short* __restrict__ qb, const unsigned short* __restrict__ vtb,
    unsigned short* __restrict__ ao) {
  __shared__ alignas(16) char pool[2][16384];   // [buf][ K 8KB | V^T 8KB ]

  const int tid = threadIdx.x;
  const int lane = tid & 63, wid = tid >> 6;
  const int g = lane >> 4, c = lane & 15;
  const int wq = wid >> 1, wk = wid & 1;

  // XCD-grouped decode: all 32 q-blocks of a bh on one XCD
  const int wg = blockIdx.x;
  const int xcd = wg & 7;
  const int idx = wg >> 3;                 // 0..191
  const int bh = xcd * 6 + (idx >> 5);
  const int qs0 = (idx & 31) * 64;
  const size_t base = (size_t)bh * SEQ * HD;

  // Q B-frags: lane (c,g) holds Q[qs0+wq*32+jq*16+c][ks*32+g*8..+7]
  bf16x8 qf[2][2];
#pragma unroll
  for (int jq = 0; jq < 2; ++jq) {
    const unsigned short* qrow = &qb[base + (size_t)(qs0 + wq * 32 + jq * 16 + c) * HD + g * 8];
    qf[jq][0] = *reinterpret_cast<const bf16x8*>(qrow);
    qf[jq][1] = *reinterpret_cast<const bf16x8*>(qrow + 32);
  }

  const char* qbB = (const char*)qb;
  const char* vtB = (const char*)vtb;
  const int oK0 = tid * 16, oK1 = tid * 16 + 4096;
  const int swK0 = oK0 ^ (((oK0 >> 7) & 7) << 4);
  const int swK1 = oK1 ^ (((oK1 >> 7) & 7) << 4);
  const int rV0 = oK0 >> 7, rV1 = oK1 >> 7;
  const int swV0 = (oK0 & 127) ^ ((rV0 & 7) << 4);
  const int swV1 = (oK1 & 127) ^ ((rV1 & 7) << 4);

  auto stage = [&](int t, int buf) {
    char* P = pool[buf];
    const size_t kQ = base * 2 + (size_t)t * 8192;   // K tile: contiguous 8KB
    gload_lds16(qbB + kQ + swK0, P + oK0);
    gload_lds16(qbB + kQ + swK1, P + oK1);
    gload_lds16(vtB + ((size_t)(bh * HD + rV0) * SEQ + t * 64) * 2 + swV0, P + 8192 + oK0);
    gload_lds16(vtB + ((size_t)(bh * HD + rV1) * SEQ + t * 64) * 2 + swV1, P + 8192 + oK1);
  };

  float l_p[2] = {0.f, 0.f};
  f32x4 o_acc[4][2] = {};  // [dn][jq]: O[d=dn*16+4g+r][q=qs0+wq*32+jq*16+c], partial wk

  const int cswz = (c & 7) << 4;

  stage(0, 0);
  asm volatile("s_waitcnt vmcnt(0)" ::: "memory");
  __builtin_amdgcn_sched_barrier(0);
  __builtin_amdgcn_s_barrier();

  for (int t = 0; t < 32; ++t) {
    const char* P = pool[t & 1];
    if (t < 31) stage(t + 1, (t + 1) & 1);

    // ---- S^T = K Q^T over this wave's 32 k-rows ----
    f32x4 sa[2][2] = {};
    __builtin_amdgcn_s_setprio(1);
#pragma unroll
    for (int jp = 0; jp < 2; ++jp) {
      const int krow = wk * 32 + jp * 16 + c;
      const bf16x8 kf0 = *reinterpret_cast<const bf16x8*>(P + krow * 128 + ((g * 16) ^ cswz));
      const bf16x8 kf1 = *reinterpret_cast<const bf16x8*>(P + krow * 128 + ((64 + g * 16) ^ cswz));
#pragma unroll
      for (int jq = 0; jq < 2; ++jq) {
        sa[jp][jq] = __builtin_amdgcn_mfma_f32_16x16x32_bf16(kf0, qf[jq][0], sa[jp][jq], 0, 0, 0);
        sa[jp][jq] = __builtin_amdgcn_mfma_f32_16x16x32_bf16(kf1, qf[jq][1], sa[jp][jq], 0, 0, 0);
      }
    }
    __builtin_amdgcn_s_setprio(0);

    // ---- fixed-max base-2 softmax + direct PV B-frag build ----
    // pvv[jq] slot e: k = wk*32 + (e>=4 ? 16:0) + 4g + (e&3)  (matches V perm)
    bf16x8 pvv[2];
#pragma unroll
    for (int jq = 0; jq < 2; ++jq) {
      float a0 = __builtin_amdgcn_exp2f(sa[0][jq][0]);
      float a1 = __builtin_amdgcn_exp2f(sa[0][jq][1]);
      float a2 = __builtin_amdgcn_exp2f(sa[0][jq][2]);
      float a3 = __builtin_amdgcn_exp2f(sa[0][jq][3]);
      float b0 = __builtin_amdgcn_exp2f(sa[1][jq][0]);
      float b1 = __builtin_amdgcn_exp2f(sa[1][jq][1]);
      float b2 = __builtin_amdgcn_exp2f(sa[1][jq][2]);
      float b3 = __builtin_amdgcn_exp2f(sa[1][jq][3]);
      l_p[jq] += ((a0 + a1) + (a2 + a3)) + ((b0 + b1) + (b2 + b3));
      uint4 u = make_uint4(cvt_pk_bf16(a0, a1), cvt_pk_bf16(a2, a3),
                           cvt_pk_bf16(b0, b1), cvt_pk_bf16(b2, b3));
      pvv[jq] = *reinterpret_cast<bf16x8*>(&u);
    }

    // ---- O^T += V^T P : K=32 MFMA; A-frag = one b128 from permuted V ----
    __builtin_amdgcn_s_setprio(1);
#pragma unroll
    for (int dn = 0; dn < 4; ++dn) {
      const int vrow = dn * 16 + c;
      const bf16x8 av = *reinterpret_cast<const bf16x8*>(
          P + 8192 + vrow * 128 + ((wk * 64 + 16 * g) ^ ((vrow & 7) << 4)));
#pragma unroll
      for (int jq = 0; jq < 2; ++jq)
        o_acc[dn][jq] = __builtin_amdgcn_mfma_f32_16x16x32_bf16(av, pvv[jq], o_acc[dn][jq], 0, 0, 0);
    }
    __builtin_amdgcn_s_setprio(0);

    // tile t+1 landed; all waves done reading buf[t&1]
    asm volatile("s_waitcnt vmcnt(0)" ::: "memory");
    __builtin_amdgcn_sched_barrier(0);
    __builtin_amdgcn_s_barrier();
  }

  // ---- epilogue: reduce l over g; O + l over the wk pair via LDS ----
#pragma unroll
  for (int jq = 0; jq < 2; ++jq) {
    float v = l_p[jq];
    v += __shfl_xor(v, 16);
    v += __shfl_xor(v, 32);
    l_p[jq] = v;
  }

  float* ex = (float*)(pool[0] + wq * 16384);  // [32 q][68] f32 + l[32]
  float* exl = ex + 32 * 68;
  if (wk == 1) {
#pragma unroll
    for (int dn = 0; dn < 4; ++dn)
#pragma unroll
      for (int jq = 0; jq < 2; ++jq)
        *reinterpret_cast<f32x4*>(&ex[(jq * 16 + c) * 68 + dn * 16 + 4 * g]) = o_acc[dn][jq];
    if (g == 0) {
      exl[c] = l_p[0];
      exl[16 + c] = l_p[1];
    }
  }
  __syncthreads();
  if (wk == 0) {
    const int b = bh / NH, h = bh % NH;
    float linv[2];
#pragma unroll
    for (int jq = 0; jq < 2; ++jq)
      linv[jq] = __builtin_amdgcn_rcpf(l_p[jq] + exl[jq * 16 + c]);
#pragma unroll
    for (int dn = 0; dn < 4; ++dn)
#pragma unroll
      for (int jq = 0; jq < 2; ++jq) {
        f32x4 o = o_acc[dn][jq];
        o += *reinterpret_cast<const f32x4*>(&ex[(jq * 16 + c) * 68 + dn * 16 + 4 * g]);
        uint2 wv = make_uint2(cvt_pk_bf16(o[0] * linv[jq], o[1] * linv[jq]),
                              cvt_pk_bf16(o[2] * linv[jq], o[3] * linv[jq]));
        *reinterpret_cast<uint2*>(
            &ao[((size_t)b * SEQ + qs0 + wq * 32 + jq * 16 + c) * DM + h * HD + dn * 16 + 4 * g]) = wv;
      }
  }
}

// ---------------------------------------------------------------------------
// Kernel 3: out = ao @ pwb^T + proj_b (bf16 in, f32 out). 64x128 tile, BK=64,
// XCD-affinity 1D grid (each XCD owns a 16-block m-panel).
// ---------------------------------------------------------------------------
__global__ __launch_bounds__(256) void proj_kernel(
    const unsigned short* __restrict__ ao, const unsigned short* __restrict__ pwb,
    const float* __restrict__ bias, float* __restrict__ out) {
  __shared__ alignas(16) char As[2][8192];    // [64 m rows][128B]
  __shared__ alignas(16) char Bs[2][16384];   // [128 n rows][128B]
  const int tid = threadIdx.x;
  const int lane = tid & 63, wid = tid >> 6;
  const int g = lane >> 4, c = lane & 15;

  // XCD-affinity decode: wg = xcd + 8*(m_local + 16*n_idx)
  const int wg = blockIdx.x;
  const int xcd = wg & 7;
  const int idx = wg >> 3;                 // 0..95
  const int m0 = (xcd * 16 + (idx & 15)) * 64;
  const int n0 = (idx >> 4) * 128;         // 0..5
  const char* Ab = (const char*)ao;
  const char* Bb = (const char*)pwb;

  auto stage = [&](int kt, int buf) {
    const int k0b = kt * 128;
#pragma unroll
    for (int i = 0; i < 2; ++i) {
      const int o = tid * 16 + i * 4096;
      const int row = o >> 7;
      const int colb = (o & 127) ^ ((row & 7) << 4);
      gload_lds16(Ab + (size_t)(m0 + row) * 1536 + k0b + colb, &As[buf][o]);
    }
#pragma unroll
    for (int i = 0; i < 4; ++i) {
      const int o = tid * 16 + i * 4096;
      const int row = o >> 7;
      const int colb = (o & 127) ^ ((row & 7) << 4);
      gload_lds16(Bb + (size_t)(n0 + row) * 1536 + k0b + colb, &Bs[buf][o]);
    }
  };

  f32x4 acc[4][2] = {};   // [mi][nj]: m = mi*16, n = wid*32 + nj*16
  stage(0, 0);

  for (int kt = 0; kt < 12; ++kt) {
    __syncthreads();
    if (kt < 11) stage(kt + 1, (kt + 1) & 1);
    const char* Ap = As[kt & 1];
    const char* Bp = Bs[kt & 1];
    bf16x8 a_f[4][2], b_f[2][2];
#pragma unroll
    for (int i = 0; i < 4; ++i) {
      const int ra = i * 16 + c;
      const int sa = (ra & 7) << 4;
#pragma unroll
      for (int ks = 0; ks < 2; ++ks)
        a_f[i][ks] = *reinterpret_cast<const bf16x8*>(Ap + ra * 128 + ((ks * 64 + g * 16) ^ sa));
    }
#pragma unroll
    for (int j = 0; j < 2; ++j) {
      const int rb = wid * 32 + j * 16 + c;
      const int sb = (rb & 7) << 4;
#pragma unroll
      for (int ks = 0; ks < 2; ++ks)
        b_f[j][ks] = *reinterpret_cast<const bf16x8*>(Bp + rb * 128 + ((ks * 64 + g * 16) ^ sb));
    }
#pragma unroll
    for (int i = 0; i < 4; ++i)
#pragma unroll
      for (int j = 0; j < 2; ++j) {
        acc[i][j] = __builtin_amdgcn_mfma_f32_16x16x32_bf16(a_f[i][0], b_f[j][0], acc[i][j], 0, 0, 0);
        acc[i][j] = __builtin_amdgcn_mfma_f32_16x16x32_bf16(a_f[i][1], b_f[j][1], acc[i][j], 0, 0, 0);
      }
  }

#pragma unroll
  for (int j = 0; j < 2; ++j) {
    const int n = n0 + wid * 32 + j * 16 + c;
    const float bn = bias[n];
#pragma unroll
    for (int i = 0; i < 4; ++i)
#pragma unroll
      for (int r = 0; r < 4; ++r) {
        const int m = m0 + i * 16 + g * 4 + r;
        out[(size_t)m * DM + n] = acc[i][j][r] + bn;
      }
  }
}

extern "C" void kernel_launch(void* const* d_in, const int* in_sizes, int n_in,
                              void* d_out, int out_size, void* d_ws, size_t ws_size,
                              hipStream_t stream) {
  const float* x = (const float*)d_in[0];
  const float* qkv_w = (const float*)d_in[1];
  const float* qkv_b = (const float*)d_in[2];
  const float* proj_w = (const float*)d_in[3];
  const float* proj_b = (const float*)d_in[4];
  float* out = (float*)d_out;

  const size_t elems = (size_t)4 * NH * SEQ * HD;  // 6291456 = B*S*DM
  unsigned short* qbuf = (unsigned short*)d_ws;
  unsigned short* vtbuf = qbuf + elems;
  unsigned short* xbf = vtbuf + elems;       // aliases aobuf (disjoint lifetimes)
  unsigned short* aobuf = xbf;
  unsigned short* wqkvbf = xbf + elems;      // 1179648
  unsigned short* wprojbf = wqkvbf + (size_t)2 * DM * DM;  // 589824

  cvt3_kernel<<<dim3(2048), 256, 0, stream>>>(
      x, xbf, (int)(elems / 8),
      qkv_w, wqkvbf, 2 * DM * DM / 8,
      proj_w, wprojbf, DM * DM / 8);

  qkv_kernel<<<dim3(768), 256, 0, stream>>>(xbf, wqkvbf, qkv_b, qbuf, vtbuf);
  attn_kernel<<<dim3(1536), 256, 0, stream>>>(qbuf, vtbuf, aobuf);
  proj_kernel<<<dim3(768), 256, 0, stream>>>(aobuf, wprojbf, proj_b, out);
}